// Round 16
// baseline (248.261 us; speedup 1.0000x reference)
//
#include <hip/hip_runtime.h>
#include <hip/hip_bf16.h>

typedef _Float16 f16;
typedef f16 f16x8 __attribute__((ext_vector_type(8)));
typedef f16 f16x2 __attribute__((ext_vector_type(2)));
typedef float f32x4 __attribute__((ext_vector_type(4)));
typedef unsigned int u32;

#define MFMA16(a, b, c) __builtin_amdgcn_mfma_f32_16x16x32_f16((a), (b), (c), 0, 0, 0)

__device__ __forceinline__ u32 pkrz(float a, float b) {
    auto r = __builtin_amdgcn_cvt_pkrtz(a, b);
    return __builtin_bit_cast(u32, r);
}
__device__ __forceinline__ u32 pkmax0(u32 x) {
    f16x2 h = __builtin_bit_cast(f16x2, x);
    f16x2 z = {(f16)0.f, (f16)0.f};
    f16x2 m = __builtin_elementwise_max(h, z);
    return __builtin_bit_cast(u32, m);
}
__device__ __forceinline__ u32 pkrelu(float a, float b) {
    return pkmax0(pkrz(a, b));
}

union U8 { f16x8 h; u32 w[4]; };

// ---- ws layout (float offsets) ----
#define OFF_REL    0          // 4096 floats: rel[b*256+d]
#define OFF_Y      4096       // 1,089,536 floats: [spt_pos 20480][spt_neg 20480][qry 1048576]
#define OFF_PROTO  1093632    // 4096
#define OFF_SNEG   1097728    // 4096
#define OFF_W      1101828    // f16 region: 29 frags * 64 lanes * 8 halves

// ---------------- prep: rel + one-time weight fragment packing ----------------
// Hidden-channel permutation: B-position (kk,g,i) holds C-slot
// (2kk + (i>>2))*16 + g*4 + (i&3) of the previous layer, so the layer
// transition is pure in-register relu+pack (no LDS / shuffles).
__global__ void k_prep(const float* __restrict__ sup, const float* __restrict__ supn,
                       const float* __restrict__ w1, const float* __restrict__ b1,
                       const float* __restrict__ w2, const float* __restrict__ w3,
                       const float* __restrict__ w4, float* __restrict__ ws)
{
    int tid = threadIdx.x;
    if (blockIdx.x < 16) {
        int idx = blockIdx.x * 256 + tid;     // (b,d)
        int b = idx >> 8, d = idx & 255;
        float acc = 0.f;
        #pragma unroll
        for (int n = 0; n < 5; n++) {
            const float* base = sup + ((b * 5 + n) * 2) * 256 + d;
            acc += base[256] - base[0];
        }
        ws[OFF_REL + idx] = acc * 0.2f;
    } else {
        f16* wf = (f16*)(ws + OFF_W);
        for (int id = tid; id < 29 * 64; id += 256) {
            int frag = id >> 6, lane = id & 63;
            int g = lane >> 4, cr = lane & 15, kb = g * 8;
            float vals[8];
            if (frag < 8) {                       // L1: W1 (128x3) + b1 folded at k==3
                int out = frag * 16 + cr;
                #pragma unroll
                for (int i = 0; i < 8; i++) {
                    int k = kb + i;
                    vals[i] = (k < 3) ? w1[out * 3 + k] : (k == 3 ? b1[out] : 0.f);
                }
            } else if (frag < 24) {               // L2: W2 (64x128), permuted input cols
                int f = frag - 8; int t = f >> 2, kk = f & 3; int out = t * 16 + cr;
                #pragma unroll
                for (int i = 0; i < 8; i++) {
                    int u = (2 * kk + (i >> 2)) * 16 + g * 4 + (i & 3);
                    vals[i] = w2[out * 128 + u];
                }
            } else if (frag < 28) {               // L3: W3 (32x64), permuted input cols
                int f = frag - 24; int t = f >> 1, kk = f & 1; int out = t * 16 + cr;
                #pragma unroll
                for (int i = 0; i < 8; i++) {
                    int u = (2 * kk + (i >> 2)) * 16 + g * 4 + (i & 3);
                    vals[i] = w3[out * 64 + u];
                }
            } else {                              // L4: W4 (1x32), permuted, rows 1..15 zero
                #pragma unroll
                for (int i = 0; i < 8; i++) {
                    int u = (i >> 2) * 16 + g * 4 + (i & 3);
                    vals[i] = (cr == 0) ? w4[u] : 0.f;
                }
            }
            #pragma unroll
            for (int i = 0; i < 8; i++) wf[id * 8 + i] = (f16)vals[i];
        }
    }
}

// ---------------- main MLP: register chain, L2 weights in LDS, lean prologue ----------------
// 1064 blocks x 4 waves x 4 iters x 64 elems = 1,089,536
// No launch_bounds: default 1024-thread cap gives VGPR<=128 (we need ~108).
// DO NOT use __launch_bounds__(256,4): caps VGPR at 64 -> massive spills
// (R13: FETCH 5MB->291MB, k_main 42->134us).
__global__ void k_main(
    const float* __restrict__ sup, const float* __restrict__ supn,
    const float* __restrict__ qry, const float* __restrict__ neg,
    const float* __restrict__ b2p, const float* __restrict__ b3p,
    const float* __restrict__ b4p, float* __restrict__ ws)
{
    __shared__ __align__(16) f16x8 w2lds[16 * 64];   // 16 KB: L2 frags
    __shared__ uint2 stage[4][64];                   // 2 KB
    const float* wsRel = ws + OFF_REL;
    float* wsY = ws + OFF_Y;
    const f16x8* wf = (const f16x8*)(ws + OFF_W);

    int tid = threadIdx.x, wv = tid >> 6, lane = tid & 63;
    int g = lane >> 4, col = lane & 15;
    const f32x4 zero4 = {0.f, 0.f, 0.f, 0.f};

    // coalesced copy of pre-packed L2 frags into LDS (1024 x 16B)
    #pragma unroll
    for (int i = 0; i < 4; i++) {
        int id = tid + 256 * i;
        w2lds[id] = wf[8 * 64 + id];
    }
    // per-lane vector loads of small-layer frags (pre-packed, coalesced 1KB each)
    f16x8 w1f[8], w3f[4], w4f;
    #pragma unroll
    for (int f = 0; f < 8; f++) w1f[f] = wf[f * 64 + lane];
    #pragma unroll
    for (int f = 0; f < 4; f++) w3f[f] = wf[(24 + f) * 64 + lane];
    w4f = wf[28 * 64 + lane];

    f32x4 bias2[4], bias3[2];
    #pragma unroll
    for (int t = 0; t < 4; t++) {
        int o = t * 16 + g * 4;
        bias2[t] = (f32x4){b2p[o], b2p[o + 1], b2p[o + 2], b2p[o + 3]};
    }
    #pragma unroll
    for (int t = 0; t < 2; t++) {
        int o = t * 16 + g * 4;
        bias3[t] = (f32x4){b3p[o], b3p[o + 1], b3p[o + 2], b3p[o + 3]};
    }
    float b4v = b4p[0];

    __syncthreads();                                  // w2lds ready

    int base = blockIdx.x * 1024 + wv * 256;

    for (int it = 0; it < 4; ++it) {
        // ---- all-lane coalesced input load: one element per lane ----
        int e = base + it * 64 + lane;
        const float* hp; int bd;
        if (e < 40960) {
            int e2 = (e < 20480) ? e : e - 20480;
            int b = e2 / 1280; int r = e2 - b * 1280;
            int n = r >> 8, d = r & 255;
            const float* srcp = (e < 20480) ? sup : supn;
            hp = srcp + ((b * 5 + n) * 2) * 256 + d;
            bd = b * 256 + d;
        } else {
            int e2 = e - 40960;
            int b = e2 >> 16, r = e2 & 65535, m = r >> 8, d = r & 255;
            hp = (m < 128) ? (qry + ((b * 128 + m) * 2) * 256 + d)
                           : (neg + ((b * 128 + (m - 128)) * 2) * 256 + d);
            bd = b * 256 + d;
        }
        float x0 = hp[0], x2 = hp[256], x1 = wsRel[bd];
        stage[wv][lane] = make_uint2(pkrz(x0, x1), pkrz(x2, 1.0f));

        #pragma unroll
        for (int jp = 0; jp < 2; ++jp) {             // 2 chunk-pairs
            U8 b1a, b1b;
            #pragma unroll
            for (int q = 0; q < 4; q++) { b1a.w[q] = 0u; b1b.w[q] = 0u; }
            if (g == 0) {
                uint2 sa = stage[wv][(2 * jp) * 16 + col];
                uint2 sb = stage[wv][(2 * jp + 1) * 16 + col];
                b1a.w[0] = sa.x; b1a.w[1] = sa.y;
                b1b.w[0] = sb.x; b1b.w[1] = sb.y;
            }

            // L1: 8 tiles x 2 chunks
            f32x4 c1a[8], c1b[8];
            #pragma unroll
            for (int t = 0; t < 8; t++) {
                c1a[t] = MFMA16(w1f[t], b1a.h, zero4);
                c1b[t] = MFMA16(w1f[t], b1b.h, zero4);
            }

            U8 b2fa[4], b2fb[4];
            #pragma unroll
            for (int kk = 0; kk < 4; kk++) {
                b2fa[kk].w[0] = pkrelu(c1a[2 * kk][0],     c1a[2 * kk][1]);
                b2fa[kk].w[1] = pkrelu(c1a[2 * kk][2],     c1a[2 * kk][3]);
                b2fa[kk].w[2] = pkrelu(c1a[2 * kk + 1][0], c1a[2 * kk + 1][1]);
                b2fa[kk].w[3] = pkrelu(c1a[2 * kk + 1][2], c1a[2 * kk + 1][3]);
                b2fb[kk].w[0] = pkrelu(c1b[2 * kk][0],     c1b[2 * kk][1]);
                b2fb[kk].w[1] = pkrelu(c1b[2 * kk][2],     c1b[2 * kk][3]);
                b2fb[kk].w[2] = pkrelu(c1b[2 * kk + 1][0], c1b[2 * kk + 1][1]);
                b2fb[kk].w[3] = pkrelu(c1b[2 * kk + 1][2], c1b[2 * kk + 1][3]);
            }

            // L2: one LDS weight read feeds both chunks
            f32x4 c2a[4], c2b[4];
            #pragma unroll
            for (int t = 0; t < 4; t++) {
                f32x4 ca = bias2[t], cb = bias2[t];
                #pragma unroll
                for (int kk = 0; kk < 4; kk++) {
                    f16x8 wfr = w2lds[(t * 4 + kk) * 64 + lane];
                    ca = MFMA16(wfr, b2fa[kk].h, ca);
                    cb = MFMA16(wfr, b2fb[kk].h, cb);
                }
                c2a[t] = ca; c2b[t] = cb;
            }

            U8 b3fa[2], b3fb[2];
            #pragma unroll
            for (int kk = 0; kk < 2; kk++) {
                b3fa[kk].w[0] = pkrelu(c2a[2 * kk][0],     c2a[2 * kk][1]);
                b3fa[kk].w[1] = pkrelu(c2a[2 * kk][2],     c2a[2 * kk][3]);
                b3fa[kk].w[2] = pkrelu(c2a[2 * kk + 1][0], c2a[2 * kk + 1][1]);
                b3fa[kk].w[3] = pkrelu(c2a[2 * kk + 1][2], c2a[2 * kk + 1][3]);
                b3fb[kk].w[0] = pkrelu(c2b[2 * kk][0],     c2b[2 * kk][1]);
                b3fb[kk].w[1] = pkrelu(c2b[2 * kk][2],     c2b[2 * kk][3]);
                b3fb[kk].w[2] = pkrelu(c2b[2 * kk + 1][0], c2b[2 * kk + 1][1]);
                b3fb[kk].w[3] = pkrelu(c2b[2 * kk + 1][2], c2b[2 * kk + 1][3]);
            }

            // L3
            f32x4 c3a[2], c3b[2];
            #pragma unroll
            for (int t = 0; t < 2; t++) {
                f32x4 ca = bias3[t], cb = bias3[t];
                #pragma unroll
                for (int kk = 0; kk < 2; kk++) {
                    ca = MFMA16(w3f[t * 2 + kk], b3fa[kk].h, ca);
                    cb = MFMA16(w3f[t * 2 + kk], b3fb[kk].h, cb);
                }
                c3a[t] = ca; c3b[t] = cb;
            }

            U8 b4fa, b4fb;
            b4fa.w[0] = pkrelu(c3a[0][0], c3a[0][1]);
            b4fa.w[1] = pkrelu(c3a[0][2], c3a[0][3]);
            b4fa.w[2] = pkrelu(c3a[1][0], c3a[1][1]);
            b4fa.w[3] = pkrelu(c3a[1][2], c3a[1][3]);
            b4fb.w[0] = pkrelu(c3b[0][0], c3b[0][1]);
            b4fb.w[1] = pkrelu(c3b[0][2], c3b[0][3]);
            b4fb.w[2] = pkrelu(c3b[1][0], c3b[1][1]);
            b4fb.w[3] = pkrelu(c3b[1][2], c3b[1][3]);

            // L4
            f32x4 c4a = MFMA16(w4f, b4fa.h, zero4);
            f32x4 c4b = MFMA16(w4f, b4fb.h, zero4);
            if (lane < 16) {
                wsY[base + it * 64 + (2 * jp) * 16 + lane]     = c4a[0] + b4v;
                wsY[base + it * 64 + (2 * jp + 1) * 16 + lane] = c4b[0] + b4v;
            }
        }
    }
}

// ---------------- proto / sneg means (once) ----------------
__global__ void k_means(float* __restrict__ ws)
{
    int idx = blockIdx.x * 256 + threadIdx.x;   // 4096 = (b,d)
    int b = idx >> 8, d = idx & 255;
    const float* y = ws + OFF_Y;
    float sp = 0.f, sn = 0.f;
    #pragma unroll
    for (int n = 0; n < 5; n++) {
        sp += y[b * 1280 + n * 256 + d];
        sn += y[20480 + b * 1280 + n * 256 + d];
    }
    ws[OFF_PROTO + idx] = sp * 0.2f;
    ws[OFF_SNEG + idx] = sn * 0.2f;
}

// ---------------- scores: 16 rows/block, proto staged in LDS once ----------------
__global__ __launch_bounds__(256) void k_scores(float* __restrict__ ws, float* __restrict__ out)
{
    __shared__ float proto[16][256];   // 16 KB
    __shared__ float snegs[256];       // 1 KB
    const float* y = ws + OFF_Y;
    int tid = threadIdx.x;
    int row0 = blockIdx.x * 16;
    int b = row0 >> 8;

    #pragma unroll
    for (int i = 0; i < 16; i++)
        proto[i][tid] = ws[OFF_PROTO + i * 256 + tid];
    snegs[tid] = ws[OFF_SNEG + b * 256 + tid];
    __syncthreads();

    int wv = tid >> 6, lane = tid & 63;

    for (int r = 0; r < 4; r++) {
        int row = row0 + wv * 4 + r;
        int m = row & 255;
        const float* q = y + 40960 + row * 256;
        float q0 = q[lane], q1 = q[lane + 64], q2 = q[lane + 128], q3 = q[lane + 192];

        float s[17];
        #pragma unroll
        for (int c = 0; c < 16; c++) {
            float d0 = q0 - proto[c][lane],       d1 = q1 - proto[c][lane + 64];
            float d2 = q2 - proto[c][lane + 128], d3 = q3 - proto[c][lane + 192];
            s[c] = d0 * d0 + d1 * d1 + d2 * d2 + d3 * d3;
        }
        {
            float d0 = q0 - snegs[lane],       d1 = q1 - snegs[lane + 64];
            float d2 = q2 - snegs[lane + 128], d3 = q3 - snegs[lane + 192];
            s[16] = d0 * d0 + d1 * d1 + d2 * d2 + d3 * d3;
        }
        #pragma unroll
        for (int off = 32; off > 0; off >>= 1) {
            #pragma unroll
            for (int c = 0; c < 17; c++) s[c] += __shfl_xor(s[c], off, 64);
        }
        float sumd = 0.f, selfd = 0.f;
        #pragma unroll
        for (int c = 0; c < 16; c++) {
            float dc = sqrtf(s[c]);
            sumd += dc;
            if (c == b) selfd = dc;
        }
        float qpos = -selfd;
        float qneg = -sqrtf(s[16]);
        float relation = -(sumd - selfd) * (1.f / 15.f);
        float delta = qpos - qneg - 0.3f * relation;

        if (lane == 0) {
            out[2 * row] = qpos;
            out[2 * row + 1] = qneg;
            out[8192 + row] = (m < 128) ? 0.f : 1.f;
            if (m < 128) out[12288 + b * 128 + m] = delta;
            else         out[14336 + b * 128 + (m - 128)] = delta;
        }
    }
}

// ---------------- delta_loss finisher: reduce over out[] ----------------
__global__ __launch_bounds__(256) void k_final(float* __restrict__ out)
{
    __shared__ float red[2][256];
    int t = threadIdx.x;
    float sp = 0.f, sn = 0.f;
    #pragma unroll
    for (int i = 0; i < 8; i++) {
        int idx = t + 256 * i;            // 2048 (b, m<128) rows
        int b = idx >> 7, m = idx & 127;
        int row = b * 256 + m;
        sp += out[2 * row];
        sn += out[2 * row + 1];
    }
    red[0][t] = sp; red[1][t] = sn;
    __syncthreads();
    #pragma unroll
    for (int off = 128; off > 0; off >>= 1) {
        if (t < off) { red[0][t] += red[0][t + off]; red[1][t] += red[1][t + off]; }
        __syncthreads();
    }
    if (t == 0) {
        float v = (red[0][0] - red[1][0]) * (1.f / 2048.f) + 1.f;
        out[16384] = fmaxf(v, 0.f);
    }
}

extern "C" void kernel_launch(void* const* d_in, const int* in_sizes, int n_in,
                              void* d_out, int out_size, void* d_ws, size_t ws_size,
                              hipStream_t stream)
{
    const float* sup  = (const float*)d_in[0];
    const float* supn = (const float*)d_in[1];
    const float* qry  = (const float*)d_in[2];
    const float* neg  = (const float*)d_in[3];
    const float* w1   = (const float*)d_in[4];
    const float* b1   = (const float*)d_in[5];
    const float* w2   = (const float*)d_in[6];
    const float* b2   = (const float*)d_in[7];
    const float* w3   = (const float*)d_in[8];
    const float* b3   = (const float*)d_in[9];
    const float* w4   = (const float*)d_in[10];
    const float* b4   = (const float*)d_in[11];
    float* ws  = (float*)d_ws;
    float* out = (float*)d_out;

    k_prep  <<<17,   256, 0, stream>>>(sup, supn, w1, b1, w2, w3, w4, ws);
    k_main  <<<1064, 256, 0, stream>>>(sup, supn, qry, neg, b2, b3, b4, ws);
    k_means <<<16,   256, 0, stream>>>(ws);
    k_scores<<<256,  256, 0, stream>>>(ws, out);
    k_final <<<1,    256, 0, stream>>>(out);
}

// Round 17
// 130.707 us; speedup vs baseline: 1.8994x; 1.8994x over previous
//
#include <hip/hip_runtime.h>
#include <hip/hip_bf16.h>

typedef _Float16 f16;
typedef f16 f16x8 __attribute__((ext_vector_type(8)));
typedef f16 f16x2 __attribute__((ext_vector_type(2)));
typedef float f32x4 __attribute__((ext_vector_type(4)));
typedef unsigned int u32;

#define MFMA16(a, b, c) __builtin_amdgcn_mfma_f32_16x16x32_f16((a), (b), (c), 0, 0, 0)

__device__ __forceinline__ u32 pkrz(float a, float b) {
    auto r = __builtin_amdgcn_cvt_pkrtz(a, b);
    return __builtin_bit_cast(u32, r);
}
__device__ __forceinline__ u32 pkmax0(u32 x) {
    f16x2 h = __builtin_bit_cast(f16x2, x);
    f16x2 z = {(f16)0.f, (f16)0.f};
    f16x2 m = __builtin_elementwise_max(h, z);
    return __builtin_bit_cast(u32, m);
}
__device__ __forceinline__ u32 pkrelu(float a, float b) {
    return pkmax0(pkrz(a, b));
}

union U8 { f16x8 h; u32 w[4]; };

// ---- ws layout (float offsets) ----
#define OFF_REL    0          // 4096 floats: rel[b*256+d]
#define OFF_Y      4096       // 1,089,536 floats: [spt_pos 20480][spt_neg 20480][qry 1048576]
#define OFF_PROTO  1093632    // 4096
#define OFF_SNEG   1097728    // 4096
#define OFF_W      1101828    // f16 region: 29 frags * 64 lanes * 8 halves

// ---------------- prep: rel + one-time weight fragment packing ----------------
// Hidden-channel permutation: B-position (kk,g,i) holds C-slot
// (2kk + (i>>2))*16 + g*4 + (i&3) of the previous layer, so the layer
// transition is pure in-register relu+pack (no LDS / shuffles).
__global__ void k_prep(const float* __restrict__ sup, const float* __restrict__ supn,
                       const float* __restrict__ w1, const float* __restrict__ b1,
                       const float* __restrict__ w2, const float* __restrict__ w3,
                       const float* __restrict__ w4, float* __restrict__ ws)
{
    int tid = threadIdx.x;
    if (blockIdx.x < 16) {
        int idx = blockIdx.x * 256 + tid;     // (b,d)
        int b = idx >> 8, d = idx & 255;
        float acc = 0.f;
        #pragma unroll
        for (int n = 0; n < 5; n++) {
            const float* base = sup + ((b * 5 + n) * 2) * 256 + d;
            acc += base[256] - base[0];
        }
        ws[OFF_REL + idx] = acc * 0.2f;
    } else {
        f16* wf = (f16*)(ws + OFF_W);
        for (int id = tid; id < 29 * 64; id += 256) {
            int frag = id >> 6, lane = id & 63;
            int g = lane >> 4, cr = lane & 15, kb = g * 8;
            float vals[8];
            if (frag < 8) {                       // L1: W1 (128x3) + b1 folded at k==3
                int out = frag * 16 + cr;
                #pragma unroll
                for (int i = 0; i < 8; i++) {
                    int k = kb + i;
                    vals[i] = (k < 3) ? w1[out * 3 + k] : (k == 3 ? b1[out] : 0.f);
                }
            } else if (frag < 24) {               // L2: W2 (64x128), permuted input cols
                int f = frag - 8; int t = f >> 2, kk = f & 3; int out = t * 16 + cr;
                #pragma unroll
                for (int i = 0; i < 8; i++) {
                    int u = (2 * kk + (i >> 2)) * 16 + g * 4 + (i & 3);
                    vals[i] = w2[out * 128 + u];
                }
            } else if (frag < 28) {               // L3: W3 (32x64), permuted input cols
                int f = frag - 24; int t = f >> 1, kk = f & 1; int out = t * 16 + cr;
                #pragma unroll
                for (int i = 0; i < 8; i++) {
                    int u = (2 * kk + (i >> 2)) * 16 + g * 4 + (i & 3);
                    vals[i] = w3[out * 64 + u];
                }
            } else {                              // L4: W4 (1x32), permuted, rows 1..15 zero
                #pragma unroll
                for (int i = 0; i < 8; i++) {
                    int u = (i >> 2) * 16 + g * 4 + (i & 3);
                    vals[i] = (cr == 0) ? w4[u] : 0.f;
                }
            }
            #pragma unroll
            for (int i = 0; i < 8; i++) wf[id * 8 + i] = (f16)vals[i];
        }
    }
}

// ---------------- main MLP: register chain, L2 weights in LDS, lean prologue ----------------
// 1064 blocks x 4 waves x 4 iters x 64 elems = 1,089,536
// __launch_bounds__(256,2) is REQUIRED: it sets the VGPR cap to 256 (usage ~108,
// no spills). Omitting it -> compiler assumes 1024-thread blocks -> VGPR capped
// at 64 -> massive scratch spills (R16: FETCH 5MB->347MB, 42->151us).
// (256,4) also caps at 64 (R13, same signature). Keep (256,2).
__global__ __launch_bounds__(256, 2) void k_main(
    const float* __restrict__ sup, const float* __restrict__ supn,
    const float* __restrict__ qry, const float* __restrict__ neg,
    const float* __restrict__ b2p, const float* __restrict__ b3p,
    const float* __restrict__ b4p, float* __restrict__ ws)
{
    __shared__ __align__(16) f16x8 w2lds[16 * 64];   // 16 KB: L2 frags
    __shared__ uint2 stage[4][64];                   // 2 KB
    const float* wsRel = ws + OFF_REL;
    float* wsY = ws + OFF_Y;
    const f16x8* wf = (const f16x8*)(ws + OFF_W);

    int tid = threadIdx.x, wv = tid >> 6, lane = tid & 63;
    int g = lane >> 4, col = lane & 15;
    const f32x4 zero4 = {0.f, 0.f, 0.f, 0.f};

    // coalesced copy of pre-packed L2 frags into LDS (1024 x 16B)
    #pragma unroll
    for (int i = 0; i < 4; i++) {
        int id = tid + 256 * i;
        w2lds[id] = wf[8 * 64 + id];
    }
    // per-lane vector loads of small-layer frags (pre-packed, coalesced 1KB each)
    f16x8 w1f[8], w3f[4], w4f;
    #pragma unroll
    for (int f = 0; f < 8; f++) w1f[f] = wf[f * 64 + lane];
    #pragma unroll
    for (int f = 0; f < 4; f++) w3f[f] = wf[(24 + f) * 64 + lane];
    w4f = wf[28 * 64 + lane];

    f32x4 bias2[4], bias3[2];
    #pragma unroll
    for (int t = 0; t < 4; t++) {
        int o = t * 16 + g * 4;
        bias2[t] = (f32x4){b2p[o], b2p[o + 1], b2p[o + 2], b2p[o + 3]};
    }
    #pragma unroll
    for (int t = 0; t < 2; t++) {
        int o = t * 16 + g * 4;
        bias3[t] = (f32x4){b3p[o], b3p[o + 1], b3p[o + 2], b3p[o + 3]};
    }
    float b4v = b4p[0];

    __syncthreads();                                  // w2lds ready

    int base = blockIdx.x * 1024 + wv * 256;

    for (int it = 0; it < 4; ++it) {
        // ---- all-lane coalesced input load: one element per lane ----
        int e = base + it * 64 + lane;
        const float* hp; int bd;
        if (e < 40960) {
            int e2 = (e < 20480) ? e : e - 20480;
            int b = e2 / 1280; int r = e2 - b * 1280;
            int n = r >> 8, d = r & 255;
            const float* srcp = (e < 20480) ? sup : supn;
            hp = srcp + ((b * 5 + n) * 2) * 256 + d;
            bd = b * 256 + d;
        } else {
            int e2 = e - 40960;
            int b = e2 >> 16, r = e2 & 65535, m = r >> 8, d = r & 255;
            hp = (m < 128) ? (qry + ((b * 128 + m) * 2) * 256 + d)
                           : (neg + ((b * 128 + (m - 128)) * 2) * 256 + d);
            bd = b * 256 + d;
        }
        float x0 = hp[0], x2 = hp[256], x1 = wsRel[bd];
        stage[wv][lane] = make_uint2(pkrz(x0, x1), pkrz(x2, 1.0f));

        #pragma unroll
        for (int jp = 0; jp < 2; ++jp) {             // 2 chunk-pairs
            U8 b1a, b1b;
            #pragma unroll
            for (int q = 0; q < 4; q++) { b1a.w[q] = 0u; b1b.w[q] = 0u; }
            if (g == 0) {
                uint2 sa = stage[wv][(2 * jp) * 16 + col];
                uint2 sb = stage[wv][(2 * jp + 1) * 16 + col];
                b1a.w[0] = sa.x; b1a.w[1] = sa.y;
                b1b.w[0] = sb.x; b1b.w[1] = sb.y;
            }

            // L1: 8 tiles x 2 chunks
            f32x4 c1a[8], c1b[8];
            #pragma unroll
            for (int t = 0; t < 8; t++) {
                c1a[t] = MFMA16(w1f[t], b1a.h, zero4);
                c1b[t] = MFMA16(w1f[t], b1b.h, zero4);
            }

            U8 b2fa[4], b2fb[4];
            #pragma unroll
            for (int kk = 0; kk < 4; kk++) {
                b2fa[kk].w[0] = pkrelu(c1a[2 * kk][0],     c1a[2 * kk][1]);
                b2fa[kk].w[1] = pkrelu(c1a[2 * kk][2],     c1a[2 * kk][3]);
                b2fa[kk].w[2] = pkrelu(c1a[2 * kk + 1][0], c1a[2 * kk + 1][1]);
                b2fa[kk].w[3] = pkrelu(c1a[2 * kk + 1][2], c1a[2 * kk + 1][3]);
                b2fb[kk].w[0] = pkrelu(c1b[2 * kk][0],     c1b[2 * kk][1]);
                b2fb[kk].w[1] = pkrelu(c1b[2 * kk][2],     c1b[2 * kk][3]);
                b2fb[kk].w[2] = pkrelu(c1b[2 * kk + 1][0], c1b[2 * kk + 1][1]);
                b2fb[kk].w[3] = pkrelu(c1b[2 * kk + 1][2], c1b[2 * kk + 1][3]);
            }

            // L2: one LDS weight read feeds both chunks
            f32x4 c2a[4], c2b[4];
            #pragma unroll
            for (int t = 0; t < 4; t++) {
                f32x4 ca = bias2[t], cb = bias2[t];
                #pragma unroll
                for (int kk = 0; kk < 4; kk++) {
                    f16x8 wfr = w2lds[(t * 4 + kk) * 64 + lane];
                    ca = MFMA16(wfr, b2fa[kk].h, ca);
                    cb = MFMA16(wfr, b2fb[kk].h, cb);
                }
                c2a[t] = ca; c2b[t] = cb;
            }

            U8 b3fa[2], b3fb[2];
            #pragma unroll
            for (int kk = 0; kk < 2; kk++) {
                b3fa[kk].w[0] = pkrelu(c2a[2 * kk][0],     c2a[2 * kk][1]);
                b3fa[kk].w[1] = pkrelu(c2a[2 * kk][2],     c2a[2 * kk][3]);
                b3fa[kk].w[2] = pkrelu(c2a[2 * kk + 1][0], c2a[2 * kk + 1][1]);
                b3fa[kk].w[3] = pkrelu(c2a[2 * kk + 1][2], c2a[2 * kk + 1][3]);
                b3fb[kk].w[0] = pkrelu(c2b[2 * kk][0],     c2b[2 * kk][1]);
                b3fb[kk].w[1] = pkrelu(c2b[2 * kk][2],     c2b[2 * kk][3]);
                b3fb[kk].w[2] = pkrelu(c2b[2 * kk + 1][0], c2b[2 * kk + 1][1]);
                b3fb[kk].w[3] = pkrelu(c2b[2 * kk + 1][2], c2b[2 * kk + 1][3]);
            }

            // L3
            f32x4 c3a[2], c3b[2];
            #pragma unroll
            for (int t = 0; t < 2; t++) {
                f32x4 ca = bias3[t], cb = bias3[t];
                #pragma unroll
                for (int kk = 0; kk < 2; kk++) {
                    ca = MFMA16(w3f[t * 2 + kk], b3fa[kk].h, ca);
                    cb = MFMA16(w3f[t * 2 + kk], b3fb[kk].h, cb);
                }
                c3a[t] = ca; c3b[t] = cb;
            }

            U8 b4fa, b4fb;
            b4fa.w[0] = pkrelu(c3a[0][0], c3a[0][1]);
            b4fa.w[1] = pkrelu(c3a[0][2], c3a[0][3]);
            b4fa.w[2] = pkrelu(c3a[1][0], c3a[1][1]);
            b4fa.w[3] = pkrelu(c3a[1][2], c3a[1][3]);
            b4fb.w[0] = pkrelu(c3b[0][0], c3b[0][1]);
            b4fb.w[1] = pkrelu(c3b[0][2], c3b[0][3]);
            b4fb.w[2] = pkrelu(c3b[1][0], c3b[1][1]);
            b4fb.w[3] = pkrelu(c3b[1][2], c3b[1][3]);

            // L4
            f32x4 c4a = MFMA16(w4f, b4fa.h, zero4);
            f32x4 c4b = MFMA16(w4f, b4fb.h, zero4);
            if (lane < 16) {
                wsY[base + it * 64 + (2 * jp) * 16 + lane]     = c4a[0] + b4v;
                wsY[base + it * 64 + (2 * jp + 1) * 16 + lane] = c4b[0] + b4v;
            }
        }
    }
}

// ---------------- proto / sneg means (once) ----------------
__global__ void k_means(float* __restrict__ ws)
{
    int idx = blockIdx.x * 256 + threadIdx.x;   // 4096 = (b,d)
    int b = idx >> 8, d = idx & 255;
    const float* y = ws + OFF_Y;
    float sp = 0.f, sn = 0.f;
    #pragma unroll
    for (int n = 0; n < 5; n++) {
        sp += y[b * 1280 + n * 256 + d];
        sn += y[20480 + b * 1280 + n * 256 + d];
    }
    ws[OFF_PROTO + idx] = sp * 0.2f;
    ws[OFF_SNEG + idx] = sn * 0.2f;
}

// ---------------- scores: 16 rows/block, proto staged in LDS once ----------------
__global__ __launch_bounds__(256) void k_scores(float* __restrict__ ws, float* __restrict__ out)
{
    __shared__ float proto[16][256];   // 16 KB
    __shared__ float snegs[256];       // 1 KB
    const float* y = ws + OFF_Y;
    int tid = threadIdx.x;
    int row0 = blockIdx.x * 16;
    int b = row0 >> 8;

    #pragma unroll
    for (int i = 0; i < 16; i++)
        proto[i][tid] = ws[OFF_PROTO + i * 256 + tid];
    snegs[tid] = ws[OFF_SNEG + b * 256 + tid];
    __syncthreads();

    int wv = tid >> 6, lane = tid & 63;

    for (int r = 0; r < 4; r++) {
        int row = row0 + wv * 4 + r;
        int m = row & 255;
        const float* q = y + 40960 + row * 256;
        float q0 = q[lane], q1 = q[lane + 64], q2 = q[lane + 128], q3 = q[lane + 192];

        float s[17];
        #pragma unroll
        for (int c = 0; c < 16; c++) {
            float d0 = q0 - proto[c][lane],       d1 = q1 - proto[c][lane + 64];
            float d2 = q2 - proto[c][lane + 128], d3 = q3 - proto[c][lane + 192];
            s[c] = d0 * d0 + d1 * d1 + d2 * d2 + d3 * d3;
        }
        {
            float d0 = q0 - snegs[lane],       d1 = q1 - snegs[lane + 64];
            float d2 = q2 - snegs[lane + 128], d3 = q3 - snegs[lane + 192];
            s[16] = d0 * d0 + d1 * d1 + d2 * d2 + d3 * d3;
        }
        #pragma unroll
        for (int off = 32; off > 0; off >>= 1) {
            #pragma unroll
            for (int c = 0; c < 17; c++) s[c] += __shfl_xor(s[c], off, 64);
        }
        float sumd = 0.f, selfd = 0.f;
        #pragma unroll
        for (int c = 0; c < 16; c++) {
            float dc = sqrtf(s[c]);
            sumd += dc;
            if (c == b) selfd = dc;
        }
        float qpos = -selfd;
        float qneg = -sqrtf(s[16]);
        float relation = -(sumd - selfd) * (1.f / 15.f);
        float delta = qpos - qneg - 0.3f * relation;

        if (lane == 0) {
            out[2 * row] = qpos;
            out[2 * row + 1] = qneg;
            out[8192 + row] = (m < 128) ? 0.f : 1.f;
            if (m < 128) out[12288 + b * 128 + m] = delta;
            else         out[14336 + b * 128 + (m - 128)] = delta;
        }
    }
}

// ---------------- delta_loss finisher: reduce over out[] ----------------
__global__ __launch_bounds__(256) void k_final(float* __restrict__ out)
{
    __shared__ float red[2][256];
    int t = threadIdx.x;
    float sp = 0.f, sn = 0.f;
    #pragma unroll
    for (int i = 0; i < 8; i++) {
        int idx = t + 256 * i;            // 2048 (b, m<128) rows
        int b = idx >> 7, m = idx & 127;
        int row = b * 256 + m;
        sp += out[2 * row];
        sn += out[2 * row + 1];
    }
    red[0][t] = sp; red[1][t] = sn;
    __syncthreads();
    #pragma unroll
    for (int off = 128; off > 0; off >>= 1) {
        if (t < off) { red[0][t] += red[0][t + off]; red[1][t] += red[1][t + off]; }
        __syncthreads();
    }
    if (t == 0) {
        float v = (red[0][0] - red[1][0]) * (1.f / 2048.f) + 1.f;
        out[16384] = fmaxf(v, 0.f);
    }
}

extern "C" void kernel_launch(void* const* d_in, const int* in_sizes, int n_in,
                              void* d_out, int out_size, void* d_ws, size_t ws_size,
                              hipStream_t stream)
{
    const float* sup  = (const float*)d_in[0];
    const float* supn = (const float*)d_in[1];
    const float* qry  = (const float*)d_in[2];
    const float* neg  = (const float*)d_in[3];
    const float* w1   = (const float*)d_in[4];
    const float* b1   = (const float*)d_in[5];
    const float* w2   = (const float*)d_in[6];
    const float* b2   = (const float*)d_in[7];
    const float* w3   = (const float*)d_in[8];
    const float* b3   = (const float*)d_in[9];
    const float* w4   = (const float*)d_in[10];
    const float* b4   = (const float*)d_in[11];
    float* ws  = (float*)d_ws;
    float* out = (float*)d_out;

    k_prep  <<<17,   256, 0, stream>>>(sup, supn, w1, b1, w2, w3, w4, ws);
    k_main  <<<1064, 256, 0, stream>>>(sup, supn, qry, neg, b2, b3, b4, ws);
    k_means <<<16,   256, 0, stream>>>(ws);
    k_scores<<<256,  256, 0, stream>>>(ws, out);
    k_final <<<1,    256, 0, stream>>>(out);
}